// Round 5
// baseline (710.686 us; speedup 1.0000x reference)
//
#include <hip/hip_runtime.h>
#include <hip/hip_bf16.h>

#define B_ROWS 16384
#define KDIM   2048   // D + H
#define NDIM   5120   // 5*H
#define HDIM   1024

// ---- fused GEMM geometry: 256 x 320 tile (320 = 5 gates x 64 h), BK=32 ----
#define BM 256
#define BN 320
#define BK 32
#define NKT (KDIM / BK)             // 64 K-tiles
#define A_BYTES (BM * BK * 2)       // 16384
#define W_BYTES (BN * BK * 2)       // 20480
#define BUFSZ   (A_BYTES + W_BYTES) // 36864
#define NBUF  4
#define LDS_BYTES (NBUF * BUFSZ)    // 147456 dynamic LDS (opt-in)

typedef __attribute__((ext_vector_type(8))) short short8;
typedef __attribute__((ext_vector_type(4))) float f32x4;

__device__ __forceinline__ void async_cp16(const void* g, void* l) {
  __builtin_amdgcn_global_load_lds(
      (const __attribute__((address_space(1))) void*)g,
      (__attribute__((address_space(3))) void*)l,
      16, 0, 0);
}

// ---------------------------------------------------------------------------
// dtype probe: x is N(0,1). If stored bf16, no 16-bit word has exponent
// field >= 137 (|v| >= 2^10). If stored fp32, half the words are uniform
// mantissa noise -> ~46% exceed it. flag=1 -> fp32 inputs, flag=0 -> bf16.
// ---------------------------------------------------------------------------
__global__ void detect_dtype(const unsigned short* __restrict__ p, int* flag) {
  __shared__ int cnt;
  if (threadIdx.x == 0) cnt = 0;
  __syncthreads();
  int h = 0;
  for (int i = threadIdx.x; i < 2048; i += 256) {
    int e = (p[i] >> 7) & 0xFF;
    if (e >= 137) h++;
  }
  atomicAdd(&cnt, h);
  __syncthreads();
  if (threadIdx.x == 0) *flag = (cnt >= 4) ? 1 : 0;
}

// ---------------------------------------------------------------------------
// pack rows [rbase, rbase+rows) of fp32 (s0|s1) -> bf16 [rows,2048].
// No-op when inputs are already bf16 (flag==0).
// ---------------------------------------------------------------------------
__global__ void pack_pair_f32(const float* __restrict__ s0, const float* __restrict__ s1,
                              __hip_bfloat16* __restrict__ dst, const int* __restrict__ flag,
                              long rbase, long total) {
  if (*flag == 0) return;
  long idx = ((long)blockIdx.x * blockDim.x + threadIdx.x) * 8;
  if (idx >= total) return;
  int  k = (int)(idx & (KDIM - 1));
  long r = (idx >> 11) + rbase;
  const float* s = (k < 1024) ? (s0 + r * 1024 + k) : (s1 + r * 1024 + (k - 1024));
  float4 v0 = ((const float4*)s)[0];
  float4 v1 = ((const float4*)s)[1];
  union { short8 v; __hip_bfloat16 e[8]; } u;
  u.e[0] = __float2bfloat16(v0.x); u.e[1] = __float2bfloat16(v0.y);
  u.e[2] = __float2bfloat16(v0.z); u.e[3] = __float2bfloat16(v0.w);
  u.e[4] = __float2bfloat16(v1.x); u.e[5] = __float2bfloat16(v1.y);
  u.e[6] = __float2bfloat16(v1.z); u.e[7] = __float2bfloat16(v1.w);
  *(short8*)(dst + idx) = u.v;
}

// ---------------------------------------------------------------------------
// pack W (Wx|Uh fp32) -> bf16 in GATE-INTERLEAVED row order:
//   Wp[hg*320 + wg*80 + g*16 + t][k] = W[g*1024 + hg*64 + wg*16 + t][k]
// so the GEMM's W staging reads CONTIGUOUS rows (round-2's proven pattern)
// while keeping all 5 gates of one h lane-local in the MFMA C layout.
// One block = one permuted row (2048 elems, coalesced float4 reads).
// ---------------------------------------------------------------------------
__global__ void pack_w_gate(const float* __restrict__ Wx, const float* __restrict__ Uh,
                            __hip_bfloat16* __restrict__ dst, const int* __restrict__ flag) {
  if (*flag == 0) return;
  long idx = ((long)blockIdx.x * blockDim.x + threadIdx.x) * 8;
  const int k  = (int)(idx & (KDIM - 1));
  const int np = (int)(idx >> 11);         // permuted row 0..5119
  const int hg = np / 320;
  const int r3 = np - hg * 320;
  const int wg = r3 / 80;
  const int r8 = r3 - wg * 80;
  const int g  = r8 >> 4;
  const int t  = r8 & 15;
  const long row = (long)g * 1024 + hg * 64 + wg * 16 + t;
  const float* s = (k < 1024) ? (Wx + row * 1024 + k) : (Uh + row * 1024 + (k - 1024));
  float4 v0 = ((const float4*)s)[0];
  float4 v1 = ((const float4*)s)[1];
  union { short8 v; __hip_bfloat16 e[8]; } u;
  u.e[0] = __float2bfloat16(v0.x); u.e[1] = __float2bfloat16(v0.y);
  u.e[2] = __float2bfloat16(v0.z); u.e[3] = __float2bfloat16(v0.w);
  u.e[4] = __float2bfloat16(v1.x); u.e[5] = __float2bfloat16(v1.y);
  u.e[6] = __float2bfloat16(v1.z); u.e[7] = __float2bfloat16(v1.w);
  *(short8*)(dst + idx) = u.v;
}

// ---------------------------------------------------------------------------
// Fused GEMM + LSTM epilogue. 256x320 tile, BK=32, 4 LDS buffers, depth-3
// counted-vmcnt prefetch. Plain 2D grid (n-fastest): default round-robin
// dispatch gives each XCD ~2 h-groups -> W slice ~2.6 MB L2-resident
// (round-4's XCD swizzle inverted this and regressed; reverted).
//
// fl=1: W staged from gate-permuted Wbf, rows CONTIGUOUS (hg*320 + j*16+..).
// fl=0: W staged scattered from Wx/Uh (correctness fallback).
// LSTM update is lane-local in acc[mi][g][r]. No G round-trip.
//
// LDS swizzle (verified SQ_LDS_BANK_CONFLICT=0): slot chunk sc at row sr
// holds data chunk sc ^ ((sr>>1)&3); staged via pre-swizzled global source
// (lane-const (l&3)^((l>>3)&3)); read with lane-const
// swz = ((l>>4)^((frow>>1)&3))<<4.
//
// Waves 0-3 stage 5 loads/tile (vmcnt(15)); waves 4-7 stage 4 (vmcnt(12)).
// ---------------------------------------------------------------------------
__global__ __launch_bounds__(512, 2) void gemm_fused(
    const __hip_bfloat16* __restrict__ Abf, const __hip_bfloat16* __restrict__ Wbf,
    const void* __restrict__ xr, const void* __restrict__ hr,
    const void* __restrict__ Wxr, const void* __restrict__ Uhr,
    const void* __restrict__ cpr, const void* __restrict__ dwr,
    const void* __restrict__ bxr, const void* __restrict__ bhr,
    float* __restrict__ out, const int* __restrict__ flag, int row_base) {
  extern __shared__ char lds[];

  const int tid = threadIdx.x;
  const int w   = tid >> 6;     // wave 0..7
  const int l   = tid & 63;

  const int hg  = blockIdx.x;        // h-group 0..15
  const int m0l = blockIdx.y * BM;   // chunk-local row base
  const int h0  = hg * 64;

  const int wm = w >> 2;   // 0..1
  const int wn = w & 3;    // 0..3

  const int fl = *flag;
  const int dc = (l & 3) ^ ((l >> 3) & 3);   // staged data chunk (lane-const)

  // --- A staging: 16 instr/block = 2/wave. Instr i covers tile rows
  //     w*32 + i*16 + (l>>2), data chunk dc.
  const __hip_bfloat16 *srcA0, *srcA1;
  long dA;
  {
    const int r0 = m0l + w * 32 + (l >> 2);
    if (fl) {
      srcA0 = Abf + (long)r0 * KDIM + dc * 8;
      srcA1 = Abf + (long)(r0 + 16) * KDIM + dc * 8;
      dA = 1024;
    } else {
      srcA0 = (const __hip_bfloat16*)xr + (long)(row_base + r0) * 1024 + dc * 8;
      srcA1 = (const __hip_bfloat16*)xr + (long)(row_base + r0 + 16) * 1024 + dc * 8;
      dA = (const __hip_bfloat16*)hr - (const __hip_bfloat16*)xr;
    }
  }

  // --- W staging: 20 instr/block. wave w handles j in {w, w+8, (w<4: w+16)}.
  //     Instr j covers tile rows j*16 + (l>>2), data chunk dc.
  const bool has3 = (w < 4);
  const int  jw0  = w;
  const int  jw1  = w + 8;
  const int  jw2  = has3 ? (w + 16) : (w + 8);   // dup when unused
  const __hip_bfloat16 *srcW0, *srcW1, *srcW2;
  long dW;
  if (fl) {
    // permuted Wbf: contiguous rows hg*320 + j*16 + (l>>2), stride KDIM
    srcW0 = Wbf + ((long)hg * 320 + jw0 * 16 + (l >> 2)) * KDIM + dc * 8;
    srcW1 = Wbf + ((long)hg * 320 + jw1 * 16 + (l >> 2)) * KDIM + dc * 8;
    srcW2 = Wbf + ((long)hg * 320 + jw2 * 16 + (l >> 2)) * KDIM + dc * 8;
    dW = 1024;
  } else {
    const __hip_bfloat16* wbase = (const __hip_bfloat16*)Wxr;
    dW = (const __hip_bfloat16*)Uhr - (const __hip_bfloat16*)Wxr;
    const int j0g = jw0 % 5, j0w = jw0 / 5;
    const int j1g = jw1 % 5, j1w = jw1 / 5;
    const int j2g = jw2 % 5, j2w = jw2 / 5;
    srcW0 = wbase + ((long)j0g * 1024 + h0 + j0w * 16 + (l >> 2)) * 1024 + dc * 8;
    srcW1 = wbase + ((long)j1g * 1024 + h0 + j1w * 16 + (l >> 2)) * 1024 + dc * 8;
    srcW2 = wbase + ((long)j2g * 1024 + h0 + j2w * 16 + (l >> 2)) * 1024 + dc * 8;
  }

#define STAGE(T) do {                                                        \
    const int  b_  = (T) & 3;                                                \
    const int  k0_ = (T) * BK;                                               \
    const long koA_ = (k0_ < 1024) ? (long)k0_ : (dA + (k0_ - 1024));        \
    const long koW_ = (k0_ < 1024) ? (long)k0_ : (dW + (k0_ - 1024));        \
    char* lb_ = lds + b_ * BUFSZ;                                            \
    async_cp16(srcA0 + koA_, lb_ + w * 2048 + l * 16);                       \
    async_cp16(srcA1 + koA_, lb_ + w * 2048 + 1024 + l * 16);                \
    async_cp16(srcW0 + koW_, lb_ + A_BYTES + jw0 * 1024 + l * 16);           \
    async_cp16(srcW1 + koW_, lb_ + A_BYTES + jw1 * 1024 + l * 16);           \
    if (has3)                                                                \
      async_cp16(srcW2 + koW_, lb_ + A_BYTES + jw2 * 1024 + l * 16);         \
  } while (0)

  f32x4 acc[8][5] = {};
  const int frow  = l & 15;
  const int swz   = ((l >> 4) ^ ((frow >> 1) & 3)) << 4;  // lane-const
  const int aoff0 = (wm * 128 + frow) * 64;               // A row byte base
  const int woff0 = A_BYTES + (wn * 80 + frow) * 64;      // W row byte base

#define COMPUTE(T) do {                                                      \
    const char* ba_ = lds + ((T) & 3) * BUFSZ;                               \
    short8 af_[8], wf_[5];                                                   \
    _Pragma("unroll")                                                        \
    for (int nj = 0; nj < 5; ++nj)                                           \
      wf_[nj] = *(const short8*)(ba_ + woff0 + nj * 1024 + swz);             \
    _Pragma("unroll")                                                        \
    for (int mi = 0; mi < 8; ++mi)                                           \
      af_[mi] = *(const short8*)(ba_ + aoff0 + mi * 1024 + swz);             \
    __builtin_amdgcn_s_setprio(1);                                           \
    _Pragma("unroll")                                                        \
    for (int mi = 0; mi < 8; ++mi)                                           \
      _Pragma("unroll")                                                      \
      for (int nj = 0; nj < 5; ++nj)                                         \
        acc[mi][nj] = __builtin_amdgcn_mfma_f32_16x16x32_bf16(               \
            af_[mi], wf_[nj], acc[mi][nj], 0, 0, 0);                         \
    __builtin_amdgcn_s_setprio(0);                                           \
  } while (0)

  STAGE(0); STAGE(1); STAGE(2);

  // main loop: depth-3 prefetch; per-wave exact counted vmcnt, never 0
  for (int t = 0; t < NKT - 3; ++t) {
    __builtin_amdgcn_s_barrier();            // all waves done reading buf[(t+3)&3]
    __builtin_amdgcn_sched_barrier(0);
    STAGE(t + 3);
    if (has3) { asm volatile("s_waitcnt vmcnt(15)" ::: "memory"); }
    else      { asm volatile("s_waitcnt vmcnt(12)" ::: "memory"); }
    __builtin_amdgcn_sched_barrier(0);
    __builtin_amdgcn_s_barrier();            // tile t visible to all waves
    __builtin_amdgcn_sched_barrier(0);
    COMPUTE(t);
  }
  // tail: drain
  for (int t = NKT - 3; t < NKT; ++t) {
    __builtin_amdgcn_s_barrier();
    asm volatile("s_waitcnt vmcnt(0)" ::: "memory");
    __builtin_amdgcn_sched_barrier(0);
    __builtin_amdgcn_s_barrier();
    __builtin_amdgcn_sched_barrier(0);
    COMPUTE(t);
  }

#undef STAGE
#undef COMPUTE

  // ---- fused LSTM epilogue: all 5 gates of h are lane-local ----
  // C layout (m89): col = lane&15 -> gate frag nj = gate g; row = (l>>4)*4 + r
  const int hh = h0 + wn * 16 + frow;     // global h index (0..1023)
  float bsum[5];
#pragma unroll
  for (int g = 0; g < 5; ++g) {
    if (fl) {
      bsum[g] = ((const float*)bxr)[g * 1024 + hh] + ((const float*)bhr)[g * 1024 + hh];
    } else {
      bsum[g] = __bfloat162float(((const __hip_bfloat16*)bxr)[g * 1024 + hh])
              + __bfloat162float(((const __hip_bfloat16*)bhr)[g * 1024 + hh]);
    }
  }
  const long orow0 = (long)row_base + m0l + wm * 128 + (l >> 4) * 4;
  float* outc = out + (long)B_ROWS * HDIM;
#pragma unroll
  for (int mi = 0; mi < 8; ++mi) {
#pragma unroll
    for (int r = 0; r < 4; ++r) {
      const long idx = (orow0 + mi * 16 + r) * HDIM + hh;
      float cp, dv;
      if (fl) {
        cp = ((const float*)cpr)[idx];
        dv = ((const float*)dwr)[idx];
      } else {
        cp = __bfloat162float(((const __hip_bfloat16*)cpr)[idx]);
        dv = __bfloat162float(((const __hip_bfloat16*)dwr)[idx]);
      }
      const float gi = acc[mi][0][r] + bsum[0];
      const float gf = acc[mi][1][r] + bsum[1];
      const float go = acc[mi][2][r] + bsum[2];
      const float gc = acc[mi][3][r] + bsum[3];
      const float gs = acc[mi][4][r] + bsum[4];
      const float it = 1.f / (1.f + __expf(-gi));
      const float ft = 1.f / (1.f + __expf(-gf));
      const float ot = 1.f / (1.f + __expf(-go));
      const float ch = tanhf(gc);
      const float st = (1.f / (1.f + __expf(-gs))) * dv;
      const float ct = ft * cp + it * ch * st;
      out[idx]  = ot * tanhf(ct);
      outc[idx] = ct;
    }
  }
}

// ---------------------------------------------------------------------------
extern "C" void kernel_launch(void* const* d_in, const int* in_sizes, int n_in,
                              void* d_out, int out_size, void* d_ws, size_t ws_size,
                              hipStream_t stream) {
  const void* x      = d_in[0];
  const void* h_prev = d_in[1];
  const void* c_prev = d_in[2];
  const void* dw     = d_in[3];
  const void* Wx     = d_in[4];
  const void* bx     = d_in[5];
  const void* Uh     = d_in[6];
  const void* bh     = d_in[7];

  // one-time opt-in to 144 KiB dynamic LDS (host-side, graph-safe)
  static int lds_attr_done = 0;
  if (!lds_attr_done) {
    hipFuncSetAttribute((const void*)gemm_fused,
                        hipFuncAttributeMaxDynamicSharedMemorySize, LDS_BYTES);
    lds_attr_done = 1;
  }

  // chunk count chosen from ws_size (host-constant -> graph-safe)
  const size_t wbf_bytes = (size_t)NDIM * KDIM * 2;  // 20 MiB
  int nc = 32;
  for (int c = 1; c <= 32; c <<= 1) {
    size_t need = 256 + wbf_bytes
                + (size_t)(B_ROWS / c) * KDIM * 2;   // Abf chunk
    if (need <= ws_size) { nc = c; break; }
  }
  const long rows = B_ROWS / nc;

  char* ws = (char*)d_ws;
  int* flag = (int*)ws;
  __hip_bfloat16* Wbf = (__hip_bfloat16*)(ws + 256);
  __hip_bfloat16* Abf = (__hip_bfloat16*)(ws + 256 + wbf_bytes);

  detect_dtype<<<1, 256, 0, stream>>>((const unsigned short*)x, flag);

  pack_w_gate<<<(int)(((long)NDIM * KDIM) / 2048), 256, 0, stream>>>(
      (const float*)Wx, (const float*)Uh, Wbf, flag);

  for (int c = 0; c < nc; ++c) {
    long rbase = c * rows;
    pack_pair_f32<<<(int)rows, 256, 0, stream>>>(
        (const float*)x, (const float*)h_prev, Abf, flag, rbase, rows * KDIM);
    dim3 grid(NDIM / BN, (int)(rows / BM));
    gemm_fused<<<grid, 512, LDS_BYTES, stream>>>(
        Abf, Wbf, x, h_prev, Wx, Uh, c_prev, dw, bx, bh,
        (float*)d_out, flag, (int)rbase);
  }
}

// Round 6
// 698.420 us; speedup vs baseline: 1.0176x; 1.0176x over previous
//
#include <hip/hip_runtime.h>
#include <hip/hip_bf16.h>

#define B_ROWS 16384
#define KDIM   2048   // D + H
#define NDIM   5120   // 5*H
#define HDIM   1024

// ---- fused GEMM geometry: 256 x 320 tile, BK=64, 4-phase schedule ----
#define BM 256
#define BN 320
#define BK 64
#define NKT (KDIM / BK)             // 32 K-tiles
// per-buffer layout: A_klo[256][32] @0 (16K) | A_khi @16K | W_klo[320][32] @32K (20K) | W_khi @52K
#define A_HALF  16384
#define W_HALF  20480
#define W_BASE  32768
#define BUFSZ   73728               // one K-tile (both k-halves, A+W)
#define LDS_BYTES (2 * BUFSZ)       // 147456 dynamic LDS (opt-in)

typedef __attribute__((ext_vector_type(8))) short short8;
typedef __attribute__((ext_vector_type(4))) float f32x4;

__device__ __forceinline__ void async_cp16(const void* g, void* l) {
  __builtin_amdgcn_global_load_lds(
      (const __attribute__((address_space(1))) void*)g,
      (__attribute__((address_space(3))) void*)l,
      16, 0, 0);
}

// ---------------------------------------------------------------------------
// dtype probe: x is N(0,1). If stored bf16, no 16-bit word has exponent
// field >= 137. If fp32, ~46% of high half-words exceed it. flag=1 -> fp32.
// ---------------------------------------------------------------------------
__global__ void detect_dtype(const unsigned short* __restrict__ p, int* flag) {
  __shared__ int cnt;
  if (threadIdx.x == 0) cnt = 0;
  __syncthreads();
  int h = 0;
  for (int i = threadIdx.x; i < 2048; i += 256) {
    int e = (p[i] >> 7) & 0xFF;
    if (e >= 137) h++;
  }
  atomicAdd(&cnt, h);
  __syncthreads();
  if (threadIdx.x == 0) *flag = (cnt >= 4) ? 1 : 0;
}

// ---------------------------------------------------------------------------
// pack rows of fp32 (s0|s1) -> bf16 [rows,2048]. No-op when flag==0.
// ---------------------------------------------------------------------------
__global__ void pack_pair_f32(const float* __restrict__ s0, const float* __restrict__ s1,
                              __hip_bfloat16* __restrict__ dst, const int* __restrict__ flag,
                              long rbase, long total) {
  if (*flag == 0) return;
  long idx = ((long)blockIdx.x * blockDim.x + threadIdx.x) * 8;
  if (idx >= total) return;
  int  k = (int)(idx & (KDIM - 1));
  long r = (idx >> 11) + rbase;
  const float* s = (k < 1024) ? (s0 + r * 1024 + k) : (s1 + r * 1024 + (k - 1024));
  float4 v0 = ((const float4*)s)[0];
  float4 v1 = ((const float4*)s)[1];
  union { short8 v; __hip_bfloat16 e[8]; } u;
  u.e[0] = __float2bfloat16(v0.x); u.e[1] = __float2bfloat16(v0.y);
  u.e[2] = __float2bfloat16(v0.z); u.e[3] = __float2bfloat16(v0.w);
  u.e[4] = __float2bfloat16(v1.x); u.e[5] = __float2bfloat16(v1.y);
  u.e[6] = __float2bfloat16(v1.z); u.e[7] = __float2bfloat16(v1.w);
  *(short8*)(dst + idx) = u.v;
}

// ---------------------------------------------------------------------------
// pack W (Wx|Uh fp32) -> bf16 in GATE-INTERLEAVED row order:
//   Wp[hg*320 + wg*80 + g*16 + t][k] = W[g*1024 + hg*64 + wg*16 + t][k]
// GEMM stages contiguous Wp rows; all 5 gates of one h stay lane-local.
// ---------------------------------------------------------------------------
__global__ void pack_w_gate(const float* __restrict__ Wx, const float* __restrict__ Uh,
                            __hip_bfloat16* __restrict__ dst, const int* __restrict__ flag) {
  if (*flag == 0) return;
  long idx = ((long)blockIdx.x * blockDim.x + threadIdx.x) * 8;
  const int k  = (int)(idx & (KDIM - 1));
  const int np = (int)(idx >> 11);
  const int hg = np / 320;
  const int r3 = np - hg * 320;
  const int wg = r3 / 80;
  const int r8 = r3 - wg * 80;
  const int g  = r8 >> 4;
  const int t  = r8 & 15;
  const long row = (long)g * 1024 + hg * 64 + wg * 16 + t;
  const float* s = (k < 1024) ? (Wx + row * 1024 + k) : (Uh + row * 1024 + (k - 1024));
  float4 v0 = ((const float4*)s)[0];
  float4 v1 = ((const float4*)s)[1];
  union { short8 v; __hip_bfloat16 e[8]; } u;
  u.e[0] = __float2bfloat16(v0.x); u.e[1] = __float2bfloat16(v0.y);
  u.e[2] = __float2bfloat16(v0.z); u.e[3] = __float2bfloat16(v0.w);
  u.e[4] = __float2bfloat16(v1.x); u.e[5] = __float2bfloat16(v1.y);
  u.e[6] = __float2bfloat16(v1.z); u.e[7] = __float2bfloat16(v1.w);
  *(short8*)(dst + idx) = u.v;
}

// ---------------------------------------------------------------------------
// Fused GEMM + LSTM epilogue, 4-phase pipelined schedule (T3+T4 class).
//
// Per K-tile t (BK=64, dbuf t&1): 4 phases; phases 0/2 issue the klo/khi
// chunk of tile t+1 (4.5 loads/wave); phases 1/3 hold the counted waits
// vmcnt(5|4) (chunk issued at phase q of iter t is read at phase q of
// iter t+1 -> 3-phase landing slack; vmcnt NEVER 0 in the loop).
// Per phase: {ds_read subtile; [stage|vmcnt]; barrier; lgkmcnt(0);
// setprio(1); 20 MFMA; setprio(0); barrier}  -- m201 pattern.
//
// Data path identical to round-5 (verified): 64-B LDS rows, XOR swizzle
// (stage chunk dc = (l&3)^((l>>3)&3), read swz = ((l>>4)^((frow>>1)&3))<<4,
// measured SQ_LDS_BANK_CONFLICT=0), gate-permuted W, lane-local epilogue.
// ---------------------------------------------------------------------------
__global__ __launch_bounds__(512, 2) void gemm_fused(
    const __hip_bfloat16* __restrict__ Abf, const __hip_bfloat16* __restrict__ Wbf,
    const void* __restrict__ xr, const void* __restrict__ hr,
    const void* __restrict__ Wxr, const void* __restrict__ Uhr,
    const void* __restrict__ cpr, const void* __restrict__ dwr,
    const void* __restrict__ bxr, const void* __restrict__ bhr,
    float* __restrict__ out, const int* __restrict__ flag, int row_base) {
  extern __shared__ char lds[];

  const int tid = threadIdx.x;
  const int w   = tid >> 6;     // wave 0..7
  const int l   = tid & 63;
  const int l16 = l * 16;

  const int hg  = blockIdx.x;        // h-group 0..15 (XCD = hg%8 -> W L2-resident)
  const int m0l = blockIdx.y * BM;
  const int h0  = hg * 64;

  const int wm = w >> 2;   // 0..1
  const int wn = w & 3;    // 0..3

  const int fl = *flag;
  const int dc = (l & 3) ^ ((l >> 3) & 3);   // staged data chunk (lane-const)

  // --- A staging: instr j in {w, w+8}; rows m0l + j*16 + (l>>2), chunk dc ---
  const __hip_bfloat16 *pA0, *pA1;
  long dA;
  {
    const int r0 = m0l + w * 16 + (l >> 2);
    if (fl) {
      pA0 = Abf + (long)r0 * KDIM + dc * 8;
      pA1 = Abf + (long)(r0 + 128) * KDIM + dc * 8;
      dA = 1024;
    } else {
      pA0 = (const __hip_bfloat16*)xr + (long)(row_base + r0) * 1024 + dc * 8;
      pA1 = (const __hip_bfloat16*)xr + (long)(row_base + r0 + 128) * 1024 + dc * 8;
      dA = (const __hip_bfloat16*)hr - (const __hip_bfloat16*)xr;
    }
  }

  // --- W staging: instr j in {w, w+8, (w<4) w+16}; permuted rows ---
  const bool has3 = (w < 4);
  const int jw2 = has3 ? (w + 16) : (w + 8);
  const __hip_bfloat16 *pW0, *pW1, *pW2;
  long dW;
  if (fl) {
    pW0 = Wbf + ((long)hg * 320 + w * 16 + (l >> 2)) * KDIM + dc * 8;
    pW1 = Wbf + ((long)hg * 320 + (w + 8) * 16 + (l >> 2)) * KDIM + dc * 8;
    pW2 = Wbf + ((long)hg * 320 + jw2 * 16 + (l >> 2)) * KDIM + dc * 8;
    dW = 1024;
  } else {
    const __hip_bfloat16* wb = (const __hip_bfloat16*)Wxr;
    dW = (const __hip_bfloat16*)Uhr - (const __hip_bfloat16*)Wxr;
    const int j0 = w, j1 = w + 8, j2 = jw2;
    pW0 = wb + ((long)(j0 % 5) * 1024 + h0 + (j0 / 5) * 16 + (l >> 2)) * 1024 + dc * 8;
    pW1 = wb + ((long)(j1 % 5) * 1024 + h0 + (j1 / 5) * 16 + (l >> 2)) * 1024 + dc * 8;
    pW2 = wb + ((long)(j2 % 5) * 1024 + h0 + (j2 / 5) * 16 + (l >> 2)) * 1024 + dc * 8;
  }

  f32x4 acc[8][5] = {};
  const int frow = l & 15;
  const int swz  = ((l >> 4) ^ ((frow >> 1) & 3)) << 4;   // lane-const
  const int aoff = (wm * 128 + frow) * 64 + swz;          // + mi*1024 (16 rows)
  const int woff = (wn * 80 + frow) * 64 + swz;           // + nj*1024

#define ST_CH(KH) do {                                                        \
    async_cp16(pA0 + koA + (KH) * 32, nb + (KH) * A_HALF + w * 1024 + l16);   \
    async_cp16(pA1 + koA + (KH) * 32, nb + (KH) * A_HALF + (w + 8) * 1024 + l16); \
    async_cp16(pW0 + koW + (KH) * 32, nb + W_BASE + (KH) * W_HALF + w * 1024 + l16); \
    async_cp16(pW1 + koW + (KH) * 32, nb + W_BASE + (KH) * W_HALF + (w + 8) * 1024 + l16); \
    if (has3)                                                                 \
      async_cp16(pW2 + koW + (KH) * 32, nb + W_BASE + (KH) * W_HALF + jw2 * 1024 + l16); \
  } while (0)

#define RD_W(KK) do { _Pragma("unroll")                                       \
    for (int nj = 0; nj < 5; ++nj)                                            \
      wf[nj] = *(const short8*)(cb + W_BASE + (KK) * W_HALF + woff + nj * 1024); \
  } while (0)

#define RD_A(MH, KK) do { _Pragma("unroll")                                   \
    for (int mi = 0; mi < 4; ++mi)                                            \
      af[mi] = *(const short8*)(cb + (KK) * A_HALF + aoff + ((MH) * 4 + mi) * 1024); \
  } while (0)

#define MFMA20(MH) do { __builtin_amdgcn_s_setprio(1);                        \
    _Pragma("unroll") for (int mi = 0; mi < 4; ++mi)                          \
      _Pragma("unroll") for (int nj = 0; nj < 5; ++nj)                        \
        acc[(MH) * 4 + mi][nj] = __builtin_amdgcn_mfma_f32_16x16x32_bf16(     \
            af[mi], wf[nj], acc[(MH) * 4 + mi][nj], 0, 0, 0);                 \
    __builtin_amdgcn_s_setprio(0); } while (0)

#define SBAR  do { __builtin_amdgcn_sched_barrier(0);                         \
                   __builtin_amdgcn_s_barrier(); } while (0)
#define LGKM0 do { asm volatile("s_waitcnt lgkmcnt(0)" ::: "memory");         \
                   __builtin_amdgcn_sched_barrier(0); } while (0)
#define VMW   do { if (has3) asm volatile("s_waitcnt vmcnt(5)" ::: "memory"); \
                   else      asm volatile("s_waitcnt vmcnt(4)" ::: "memory"); \
                   __builtin_amdgcn_sched_barrier(0); } while (0)

  // ---- prologue: stage tile 0 (both k-halves) into dbuf0; wait klo(0) ----
  {
    char* nb = lds;
    const long koA = 0, koW = 0;
    ST_CH(0);
    ST_CH(1);
    VMW;   // waits klo(0); khi(0) may stay in flight (checked at iter0 ph1)
    SBAR;
  }

  for (int t = 0; t < NKT; ++t) {
    const char* cb = lds + (t & 1) * BUFSZ;
    char*       nb = lds + ((t + 1) & 1) * BUFSZ;
    const int   tn  = (t + 1) & 31;          // clamp: last iter stages dummy tile 0
    const int   k0n = tn * BK;
    const long  koA = (k0n < 1024) ? (long)k0n : (dA + (k0n - 1024));
    const long  koW = (k0n < 1024) ? (long)k0n : (dW + (k0n - 1024));
    short8 af[4], wf[5];
    // ---- ph0: klo reads (mh0) + stage klo(t+1) ----
    RD_W(0); RD_A(0, 0);
    ST_CH(0);
    SBAR; LGKM0; MFMA20(0);
    SBAR;
    // ---- ph1: klo reads (mh1); counted wait for khi(t) ----
    RD_A(1, 0);
    VMW;
    SBAR; LGKM0; MFMA20(1);
    SBAR;
    // ---- ph2: khi reads (mh0) + stage khi(t+1) ----
    RD_W(1); RD_A(0, 1);
    ST_CH(1);
    SBAR; LGKM0; MFMA20(0);
    SBAR;
    // ---- ph3: khi reads (mh1); counted wait for klo(t+1) ----
    RD_A(1, 1);
    VMW;
    SBAR; LGKM0; MFMA20(1);
    SBAR;
  }
  asm volatile("s_waitcnt vmcnt(0)" ::: "memory");  // drain dummy tail stages

#undef ST_CH
#undef RD_W
#undef RD_A
#undef MFMA20
#undef SBAR
#undef LGKM0
#undef VMW

  // ---- fused LSTM epilogue: all 5 gates of h are lane-local ----
  // C layout (m89): col = lane&15 -> gate frag nj = gate g; row = (l>>4)*4 + r
  const int hh = h0 + wn * 16 + frow;     // global h index
  float bsum[5];
#pragma unroll
  for (int g = 0; g < 5; ++g) {
    if (fl) {
      bsum[g] = ((const float*)bxr)[g * 1024 + hh] + ((const float*)bhr)[g * 1024 + hh];
    } else {
      bsum[g] = __bfloat162float(((const __hip_bfloat16*)bxr)[g * 1024 + hh])
              + __bfloat162float(((const __hip_bfloat16*)bhr)[g * 1024 + hh]);
    }
  }
  const long orow0 = (long)row_base + m0l + wm * 128 + (l >> 4) * 4;
  float* outc = out + (long)B_ROWS * HDIM;
#pragma unroll
  for (int mi = 0; mi < 8; ++mi) {
#pragma unroll
    for (int r = 0; r < 4; ++r) {
      const long idx = (orow0 + mi * 16 + r) * HDIM + hh;
      float cp, dv;
      if (fl) {
        cp = ((const float*)cpr)[idx];
        dv = ((const float*)dwr)[idx];
      } else {
        cp = __bfloat162float(((const __hip_bfloat16*)cpr)[idx]);
        dv = __bfloat162float(((const __hip_bfloat16*)dwr)[idx]);
      }
      const float gi = acc[mi][0][r] + bsum[0];
      const float gf = acc[mi][1][r] + bsum[1];
      const float go = acc[mi][2][r] + bsum[2];
      const float gc = acc[mi][3][r] + bsum[3];
      const float gs = acc[mi][4][r] + bsum[4];
      const float it = 1.f / (1.f + __expf(-gi));
      const float ft = 1.f / (1.f + __expf(-gf));
      const float ot = 1.f / (1.f + __expf(-go));
      const float ch = tanhf(gc);
      const float st = (1.f / (1.f + __expf(-gs))) * dv;
      const float ct = ft * cp + it * ch * st;
      out[idx]  = ot * tanhf(ct);
      outc[idx] = ct;
    }
  }
}

// ---------------------------------------------------------------------------
extern "C" void kernel_launch(void* const* d_in, const int* in_sizes, int n_in,
                              void* d_out, int out_size, void* d_ws, size_t ws_size,
                              hipStream_t stream) {
  const void* x      = d_in[0];
  const void* h_prev = d_in[1];
  const void* c_prev = d_in[2];
  const void* dw     = d_in[3];
  const void* Wx     = d_in[4];
  const void* bx     = d_in[5];
  const void* Uh     = d_in[6];
  const void* bh     = d_in[7];

  static int lds_attr_done = 0;
  if (!lds_attr_done) {
    hipFuncSetAttribute((const void*)gemm_fused,
                        hipFuncAttributeMaxDynamicSharedMemorySize, LDS_BYTES);
    lds_attr_done = 1;
  }

  const size_t wbf_bytes = (size_t)NDIM * KDIM * 2;  // 20 MiB
  int nc = 32;
  for (int c = 1; c <= 32; c <<= 1) {
    size_t need = 256 + wbf_bytes
                + (size_t)(B_ROWS / c) * KDIM * 2;   // Abf chunk
    if (need <= ws_size) { nc = c; break; }
  }
  const long rows = B_ROWS / nc;

  char* ws = (char*)d_ws;
  int* flag = (int*)ws;
  __hip_bfloat16* Wbf = (__hip_bfloat16*)(ws + 256);
  __hip_bfloat16* Abf = (__hip_bfloat16*)(ws + 256 + wbf_bytes);

  detect_dtype<<<1, 256, 0, stream>>>((const unsigned short*)x, flag);

  pack_w_gate<<<(int)(((long)NDIM * KDIM) / 2048), 256, 0, stream>>>(
      (const float*)Wx, (const float*)Uh, Wbf, flag);

  for (int c = 0; c < nc; ++c) {
    long rbase = c * rows;
    pack_pair_f32<<<(int)rows, 256, 0, stream>>>(
        (const float*)x, (const float*)h_prev, Abf, flag, rbase, rows * KDIM);
    dim3 grid(NDIM / BN, (int)(rows / BM));
    gemm_fused<<<grid, 512, LDS_BYTES, stream>>>(
        Abf, Wbf, x, h_prev, Wx, Uh, c_prev, dw, bx, bh,
        (float*)d_out, flag, (int)rbase);
  }
}